// Round 7
// baseline (1077.100 us; speedup 1.0000x reference)
//
#include <hip/hip_runtime.h>
#include <math.h>

// Chamfer distance, N=2, D=3 fp32 — grid-pruned exact NN, LDS-staged v3.
// r6 post-mortem: sorted order clusters the sparse tail into whole waves and
// r6 expanded per-lane SERIALLY (outskirt wave = 64 serial expansions); scans
// hit global with ~2 loads in flight. Fixes:
//  1) snake cell order (x reversed by y parity, y by z parity): consecutive
//     sorted cells are face-adjacent -> no x-wrap boxes.
//  2) box staged into LDS via coalesced cooperative loads; scan via broadcast
//     ds_read_b128 (~7cyc) + 4 VALU serving all 64 lane-queries.
//  3) wave-cooperative iterative expansion for ALL unsatisfied lanes at once;
//     overflow (>2048 staged) -> per-lane own-3^3+shells from global (rare).
// Exactness: scanned set covers ball(q, margin-to-scanned-box); cell_coord
// clamp is non-expansive so domain-edge faces are exhaustive; shell bound
// s*HCELL valid for clamped points (they sit beyond edge cells).
// Determinism: cell sets deterministic; fp min order-independent; fixed-order
// final reduction.

#define G 32
#define NC (G * G * G)
#define HLO -4.5f
#define HSPAN 9.0f
#define HCELL 0.28125f
#define QBLK 64
#define LDS_CAP 2048
#define P2A_BLOCKS 6
#define P2A_PAD 8

__device__ __forceinline__ int cell_coord(float x) {
    int i = (int)floorf((x - HLO) * ((float)G / HSPAN));
    return min(max(i, 0), G - 1);
}

// snake id: yy = y or G-1-y by z parity; xx = x or G-1-x by yy parity.
__device__ __forceinline__ unsigned snake_id(int ix, int iy, int iz) {
    const int yy = (iz & 1) ? (G - 1 - iy) : iy;
    const int xx = (yy & 1) ? (G - 1 - ix) : ix;
    return ((unsigned)iz * G + yy) * G + xx;
}

// contiguous sorted-array range covering physical x in [x0,x1] of row (y,z)
__device__ __forceinline__ void snake_range(const unsigned* __restrict__ tst,
                                            int zc, int yc, int x0, int x1,
                                            unsigned& lo, unsigned& hi) {
    const int yy = (zc & 1) ? (G - 1 - yc) : yc;
    const int base = (zc * G + yy) * G;
    int s0, s1;
    if (yy & 1) { s0 = G - 1 - x1; s1 = G - 1 - x0; }
    else        { s0 = x0;         s1 = x1; }
    lo = tst[base + s0];
    hi = tst[base + s1 + 1];
}

__device__ __forceinline__ void scan_glb(const float4* __restrict__ T,
                                         unsigned k, unsigned ke,
                                         float ax, float ay, float az,
                                         float& best) {
    for (; k + 2 <= ke; k += 2) {
        float4 b0 = T[k], b1 = T[k + 1];
        float d0 = fmaf(ax, b0.x, fmaf(ay, b0.y, fmaf(az, b0.z, b0.w)));
        float d1 = fmaf(ax, b1.x, fmaf(ay, b1.y, fmaf(az, b1.z, b1.w)));
        best = fminf(fminf(best, d0), d1);
    }
    if (k < ke) {
        float4 b = T[k];
        best = fminf(best, fmaf(ax, b.x, fmaf(ay, b.y, fmaf(az, b.z, b.w))));
    }
}

// ---------------- grid build / scan / scatter ----------------

__global__ __launch_bounds__(256) void grid_build(
    const float* __restrict__ c1, const float* __restrict__ c2,
    int P1, int P2, unsigned* __restrict__ hist,
    unsigned* __restrict__ cellid, unsigned* __restrict__ rank) {
    const int set = blockIdx.y;           // n*2 + cloud
    const int n = set >> 1, cl = set & 1;
    const int P = cl ? P2 : P1;
    const int i = blockIdx.x * 256 + threadIdx.x;
    if (i >= P) return;
    const float* p = (cl ? c2 + (size_t)n * P2 * 3 : c1 + (size_t)n * P1 * 3) + (size_t)i * 3;
    const unsigned c = snake_id(cell_coord(p[0]), cell_coord(p[1]), cell_coord(p[2]));
    const unsigned r = atomicAdd(&hist[(size_t)set * NC + c], 1u);
    const int poff = n * (P1 + P2) + (cl ? P1 : 0);
    cellid[poff + i] = c;
    rank[poff + i] = r;
}

__global__ __launch_bounds__(1024) void grid_scan(
    const unsigned* __restrict__ hist, unsigned* __restrict__ starts) {
    const int set = blockIdx.x;
    const unsigned* h = hist + (size_t)set * NC;
    unsigned* st = starts + (size_t)set * (NC + 1);
    const int t = threadIdx.x;
    const int CH = NC / 1024;             // 32
    unsigned s = 0;
    for (int k = 0; k < CH; ++k) s += h[t * CH + k];
    __shared__ unsigned sd[1024];
    sd[t] = s;
    __syncthreads();
    for (int off = 1; off < 1024; off <<= 1) {
        unsigned v = (t >= off) ? sd[t - off] : 0u;
        __syncthreads();
        sd[t] += v;
        __syncthreads();
    }
    unsigned run = (t == 0) ? 0u : sd[t - 1];
    for (int k = 0; k < CH; ++k) {
        st[t * CH + k] = run;
        run += h[t * CH + k];
    }
    if (t == 1023) st[NC] = run;          // sentinel = total
}

__global__ __launch_bounds__(256) void grid_scatter(
    const float* __restrict__ c1, const float* __restrict__ c2,
    int P1, int P2, const unsigned* __restrict__ starts,
    const unsigned* __restrict__ cellid, const unsigned* __restrict__ rank,
    float4* __restrict__ sorted, unsigned* __restrict__ sidx) {
    const int set = blockIdx.y;
    const int n = set >> 1, cl = set & 1;
    const int P = cl ? P2 : P1;
    const int i = blockIdx.x * 256 + threadIdx.x;
    if (i >= P) return;
    const float* p = (cl ? c2 + (size_t)n * P2 * 3 : c1 + (size_t)n * P1 * 3) + (size_t)i * 3;
    const float x = p[0], y = p[1], z = p[2];
    const int poff = n * (P1 + P2) + (cl ? P1 : 0);
    const unsigned c = cellid[poff + i];
    const unsigned pos = starts[(size_t)set * (NC + 1) + c] + rank[poff + i];
    sorted[poff + pos] = make_float4(-2.f * x, -2.f * y, -2.f * z,
                                     fmaf(x, x, fmaf(y, y, z * z)));
    sidx[poff + pos] = i;
}

// ---------------- LDS-staged wave-cooperative query ----------------

__global__ __launch_bounds__(QBLK) void grid_query(
    int P1, int P2, const unsigned* __restrict__ starts,
    const float4* __restrict__ sorted, const unsigned* __restrict__ sidx,
    float* __restrict__ mk) {
    __shared__ float4 cand[LDS_CAP];      // 32 KB
    const int zz = blockIdx.y;            // n*2 + dir
    const int n = zz >> 1, dir = zz & 1;
    const int ts = n * 2 + (dir ? 0 : 1); // target set
    const int Pq = dir ? P2 : P1;
    const int qoff = n * (P1 + P2) + (dir ? P1 : 0);
    const int toff = n * (P1 + P2) + (dir ? 0 : P1);
    if (blockIdx.x * QBLK >= Pq) return;
    const unsigned* tst = starts + (size_t)ts * (NC + 1);
    const float4* T = sorted + toff;
    const int lane = threadIdx.x;

    int qi = blockIdx.x * QBLK + lane;
    const bool valid = qi < Pq;
    qi = min(qi, Pq - 1);

    const float4 q = sorted[qoff + qi];   // snake-sorted: wave spans adjacent cells
    const unsigned orig = sidx[qoff + qi];
    const float ax = -0.5f * q.x, ay = -0.5f * q.y, az = -0.5f * q.z, qw = q.w;
    const int cx = cell_coord(ax), cy = cell_coord(ay), cz = cell_coord(az);

    // wave-wide cell bounding box, dilated +-1
    int bx0 = cx, bx1 = cx, by0 = cy, by1 = cy, bz0 = cz, bz1 = cz;
    #pragma unroll
    for (int o = 32; o; o >>= 1) {
        bx0 = min(bx0, __shfl_xor(bx0, o)); bx1 = max(bx1, __shfl_xor(bx1, o));
        by0 = min(by0, __shfl_xor(by0, o)); by1 = max(by1, __shfl_xor(by1, o));
        bz0 = min(bz0, __shfl_xor(bz0, o)); bz1 = max(bz1, __shfl_xor(bz1, o));
    }
    bx0 = max(bx0 - 1, 0); bx1 = min(bx1 + 1, G - 1);
    by0 = max(by0 - 1, 0); by1 = min(by1 + 1, G - 1);
    bz0 = max(bz0 - 1, 0); bz1 = min(bz1 + 1, G - 1);

    // scanned box (empty) and staging state
    int px0 = 1, px1 = 0, py0 = 1, py1 = 0, pz0 = 1, pz1 = 0;
    unsigned staged = 0, scanned = 0;
    float best = INFINITY;
    bool alldone = false, ok = false, ovf = false;

    for (int iter = 0; iter < 2 * G; ++iter) {
        // ---- stage (box \ prev) into LDS, cooperatively ----
        {
            const int ys = by1 - by0 + 1;
            const int rows = ys * (bz1 - bz0 + 1);
            const int nsegs = rows * 2;
            unsigned l0 = 0, h0 = 0, l1 = 0, h1 = 0;
            auto segrange = [&](int s, unsigned& lo, unsigned& hi) {
                lo = 0; hi = 0;
                const int row = s >> 1, part = s & 1;
                const int zc = bz0 + row / ys, yc = by0 + row % ys;
                const bool inprev = (zc >= pz0 && zc <= pz1 &&
                                     yc >= py0 && yc <= py1);
                int x0, x1;
                if (part == 0) { x0 = bx0; x1 = inprev ? px0 - 1 : bx1; }
                else { if (!inprev) return; x0 = px1 + 1; x1 = bx1; }
                if (x1 < x0) return;
                snake_range(tst, zc, yc, x0, x1, lo, hi);
            };
            const bool par = (nsegs <= 128);
            if (par) {
                if (lane < nsegs) segrange(lane, l0, h0);
                if (64 + lane < nsegs) segrange(64 + lane, l1, h1);
            }
            for (int s = 0; s < nsegs; ++s) {
                unsigned lo, hi;
                if (par) {
                    lo = (unsigned)__shfl((s < 64) ? (int)l0 : (int)l1, s & 63);
                    hi = (unsigned)__shfl((s < 64) ? (int)h0 : (int)h1, s & 63);
                } else segrange(s, lo, hi);
                const unsigned cnt = hi - lo;
                if (!cnt) continue;
                if (staged + cnt > LDS_CAP) { ovf = true; break; }
                for (unsigned k = lane; k < cnt; k += 64)
                    cand[staged + k] = T[lo + k];
                staged += cnt;
            }
        }
        __syncthreads();
        // ---- scan newly staged ----
        {
            unsigned k = scanned;
            for (; k + 2 <= staged; k += 2) {
                float4 b0 = cand[k], b1 = cand[k + 1];
                float d0 = fmaf(ax, b0.x, fmaf(ay, b0.y, fmaf(az, b0.z, b0.w)));
                float d1 = fmaf(ax, b1.x, fmaf(ay, b1.y, fmaf(az, b1.z, b1.w)));
                best = fminf(fminf(best, d0), d1);
            }
            if (k < staged) {
                float4 b = cand[k];
                best = fminf(best, fmaf(ax, b.x, fmaf(ay, b.y, fmaf(az, b.z, b.w))));
            }
            scanned = staged;
        }
        if (!ovf) { px0 = bx0; px1 = bx1; py0 = by0; py1 = by1; pz0 = bz0; pz1 = bz1; }
        // ---- per-lane margin vs scanned box ----
        if (px0 <= px1) {
            float mg = 1e30f;
            if (px0 > 0)     mg = fminf(mg, ax - (HLO + (float)px0 * HCELL));
            if (px1 < G - 1) mg = fminf(mg, (HLO + (float)(px1 + 1) * HCELL) - ax);
            if (py0 > 0)     mg = fminf(mg, ay - (HLO + (float)py0 * HCELL));
            if (py1 < G - 1) mg = fminf(mg, (HLO + (float)(py1 + 1) * HCELL) - ay);
            if (pz0 > 0)     mg = fminf(mg, az - (HLO + (float)pz0 * HCELL));
            if (pz1 < G - 1) mg = fminf(mg, (HLO + (float)(pz1 + 1) * HCELL) - az);
            ok = (qw + best) <= mg * mg;
        } else ok = false;
        ok = ok || !valid;
        if (__all(ok)) { alldone = true; break; }
        if (ovf) break;
        // ---- expand box by 1 (clamped) ----
        bx0 = max(px0 - 1, 0); bx1 = min(px1 + 1, G - 1);
        by0 = max(py0 - 1, 0); by1 = min(py1 + 1, G - 1);
        bz0 = max(pz0 - 1, 0); bz1 = min(pz1 + 1, G - 1);
    }

    float d2 = qw + best;
    if (!alldone && !ok) {
        // per-lane exhaustive fallback: own 3^3 + expanding shells (global).
        // Valid regardless of what was staged (extra scans only lower min).
        const int ex0 = max(cx - 1, 0), ex1 = min(cx + 1, G - 1);
        const int ey0 = max(cy - 1, 0), ey1 = min(cy + 1, G - 1);
        const int ez0 = max(cz - 1, 0), ez1 = min(cz + 1, G - 1);
        for (int zc = ez0; zc <= ez1; ++zc)
            for (int yc = ey0; yc <= ey1; ++yc) {
                unsigned lo, hi;
                snake_range(tst, zc, yc, ex0, ex1, lo, hi);
                scan_glb(T, lo, hi, ax, ay, az, best);
            }
        d2 = qw + best;
        if (!(d2 <= HCELL * HCELL)) {
            for (int s = 2; s < G; ++s) {
                for (int dz = -s; dz <= s; ++dz) {
                    const int z2 = cz + dz;
                    if ((unsigned)z2 >= G) continue;
                    const bool zf = (dz == -s) || (dz == s);
                    for (int dy = -s; dy <= s; ++dy) {
                        const int y2 = cy + dy;
                        if ((unsigned)y2 >= G) continue;
                        if (zf || dy == -s || dy == s) {
                            const int x0 = max(cx - s, 0), x1 = min(cx + s, G - 1);
                            unsigned lo, hi;
                            snake_range(tst, z2, y2, x0, x1, lo, hi);
                            scan_glb(T, lo, hi, ax, ay, az, best);
                        } else {
                            const int xl = cx - s, xh = cx + s;
                            if (xl >= 0) {
                                unsigned lo, hi;
                                snake_range(tst, z2, y2, xl, xl, lo, hi);
                                scan_glb(T, lo, hi, ax, ay, az, best);
                            }
                            if (xh <= G - 1) {
                                unsigned lo, hi;
                                snake_range(tst, z2, y2, xh, xh, lo, hi);
                                scan_glb(T, lo, hi, ax, ay, az, best);
                            }
                        }
                    }
                }
                d2 = qw + best;
                const float bnd = (float)s * HCELL;
                if (d2 <= bnd * bnd) break;
            }
        }
        d2 = qw + best;
    }
    if (valid) mk[qoff + orig] = d2;
}

// ---------------- fused final reduction (deterministic fixed order) ----------

__global__ __launch_bounds__(1024) void reduce_all(
    const float* __restrict__ mk, int P1, int P2, float* __restrict__ out) {
    const int t = threadIdx.x;
    const int off[4] = {0, P1, P1 + P2, P1 + P2 + P1};
    const int len[4] = {P1, P2, P1, P2};
    float acc[4];
    #pragma unroll
    for (int z = 0; z < 4; ++z) {
        float s = 0.f;
        const float* p = mk + off[z];
        for (int i = t; i < len[z]; i += 1024) s += p[i];
        acc[z] = s;
    }
    __shared__ float red[1024];
    float res[4];
    for (int z = 0; z < 4; ++z) {
        red[t] = acc[z];
        __syncthreads();
        for (int o = 512; o > 0; o >>= 1) {
            if (t < o) red[t] += red[t + o];
            __syncthreads();
        }
        res[z] = red[0];
        __syncthreads();
    }
    if (t == 0) {
        out[0] = res[0] / (float)P1 + res[1] / (float)P2;
        out[1] = res[2] / (float)P1 + res[3] / (float)P2;
    }
}

// ---------------- fallback brute-force path (r2 config) ----------------

#define BLOCK 256
#define QPT 4
#define SEG 384

__device__ __forceinline__ unsigned fkey(float f) {
    unsigned u = __float_as_uint(f);
    unsigned mask = (unsigned)((int)u >> 31) | 0x80000000u;
    return u ^ mask;
}
__device__ __forceinline__ float fdec(unsigned k) {
    unsigned mask = (k & 0x80000000u) ? 0x80000000u : 0xFFFFFFFFu;
    return __uint_as_float(k ^ mask);
}

__global__ __launch_bounds__(BLOCK) void chamfer_pass1(
    const float* __restrict__ c1, const float* __restrict__ c2,
    int P1, int P2, unsigned* __restrict__ mk_all) {
    const int z = blockIdx.z;
    const int n = z >> 1, dir = z & 1;
    const int Pq = dir ? P2 : P1;
    const int Pt = dir ? P1 : P2;
    const float* Q = (dir ? c2 : c1) + (size_t)n * Pq * 3;
    const float* T = (dir ? c1 : c2) + (size_t)n * Pt * 3;
    unsigned* mk = mk_all + (size_t)n * (P1 + P2) + (dir ? P1 : 0);

    __shared__ float4 tile[SEG];
    const int t0 = blockIdx.y * SEG;
    const int nt = Pt - t0;
    for (int j = threadIdx.x; j < SEG; j += BLOCK) {
        float4 v;
        if (j < nt) {
            const float* p = T + (size_t)(t0 + j) * 3;
            float x = p[0], y = p[1], w = p[2];
            v = make_float4(-2.f * x, -2.f * y, -2.f * w,
                            fmaf(x, x, fmaf(y, y, w * w)));
        } else {
            v = make_float4(0.f, 0.f, 0.f, INFINITY);
        }
        tile[j] = v;
    }
    __syncthreads();

    const int qbase = blockIdx.x * (BLOCK * QPT) + threadIdx.x;
    float ax[QPT], ay[QPT], az[QPT], sq[QPT], m[QPT];
    #pragma unroll
    for (int k = 0; k < QPT; ++k) {
        const int qi = qbase + k * BLOCK;
        ax[k] = 0.f; ay[k] = 0.f; az[k] = 0.f;
        if (qi < Pq) {
            const float* p = Q + (size_t)qi * 3;
            ax[k] = p[0]; ay[k] = p[1]; az[k] = p[2];
        }
        sq[k] = fmaf(ax[k], ax[k], fmaf(ay[k], ay[k], az[k] * az[k]));
        m[k] = INFINITY;
    }
    #pragma unroll 4
    for (int j = 0; j < SEG; j += 2) {
        float4 b0 = tile[j];
        float4 b1 = tile[j + 1];
        #pragma unroll
        for (int k = 0; k < QPT; ++k) {
            float d0 = fmaf(ax[k], b0.x, fmaf(ay[k], b0.y, fmaf(az[k], b0.z, b0.w)));
            float d1 = fmaf(ax[k], b1.x, fmaf(ay[k], b1.y, fmaf(az[k], b1.z, b1.w)));
            m[k] = fminf(fminf(m[k], d0), d1);
        }
    }
    #pragma unroll
    for (int k = 0; k < QPT; ++k) {
        const int qi = qbase + k * BLOCK;
        if (qi < Pq) atomicMin(&mk[qi], fkey(sq[k] + m[k]));
    }
}

__global__ __launch_bounds__(256) void pass2a_key(
    const unsigned* __restrict__ mk_all, int P1, int P2,
    float* __restrict__ partial) {
    const int z = blockIdx.y;
    const int b = blockIdx.x;
    const int n = z >> 1, dir = z & 1;
    const int Pq = dir ? P2 : P1;
    const unsigned* mk = mk_all + (size_t)n * (P1 + P2) + (dir ? P1 : 0);
    const int span = (Pq + P2A_BLOCKS - 1) / P2A_BLOCKS;
    const int lo = b * span;
    const int hi = min(lo + span, Pq);
    float s = 0.f;
    for (int q = lo + threadIdx.x; q < hi; q += 256) s += fdec(mk[q]);
    __shared__ float red[256];
    red[threadIdx.x] = s;
    __syncthreads();
    for (int off = 128; off > 0; off >>= 1) {
        if (threadIdx.x < off) red[threadIdx.x] += red[threadIdx.x + off];
        __syncthreads();
    }
    if (threadIdx.x == 0) partial[z * P2A_PAD + b] = red[0];
}

__global__ void pass2b(const float* __restrict__ partial,
                       int P1, int P2, float* __restrict__ out) {
    int n = threadIdx.x;
    if (n < 2) {
        float sA = 0.f, sB = 0.f;
        for (int b = 0; b < P2A_BLOCKS; ++b) {
            sA += partial[(n * 2 + 0) * P2A_PAD + b];
            sB += partial[(n * 2 + 1) * P2A_PAD + b];
        }
        out[n] = sA / (float)P1 + sB / (float)P2;
    }
}

// ---------------- launch ----------------

static inline size_t al256(size_t x) { return (x + 255) & ~(size_t)255; }

extern "C" void kernel_launch(void* const* d_in, const int* in_sizes, int n_in,
                              void* d_out, int out_size, void* d_ws, size_t ws_size,
                              hipStream_t stream) {
    const float* c1 = (const float*)d_in[0];
    const float* c2 = (const float*)d_in[1];
    const int N = 2;
    const int P1 = in_sizes[0] / (N * 3);
    const int P2 = in_sizes[1] / (N * 3);
    const int TP = N * (P1 + P2);
    const int Pmax = P1 > P2 ? P1 : P2;

    // ws layout (256-aligned)
    size_t o_hist = 0;
    size_t o_starts = al256(o_hist + (size_t)4 * NC * 4);
    size_t o_cellid = al256(o_starts + (size_t)4 * (NC + 1) * 4);
    size_t o_rank = al256(o_cellid + (size_t)TP * 4);
    size_t o_sidx = al256(o_rank + (size_t)TP * 4);
    size_t o_mk = al256(o_sidx + (size_t)TP * 4);
    size_t o_part = al256(o_mk + (size_t)TP * 4);
    size_t o_sorted = al256(o_part + (size_t)4 * P2A_PAD * 4);
    size_t need = o_sorted + (size_t)TP * 16;

    char* ws = (char*)d_ws;
    float* partial = (float*)(ws + o_part);

    if (ws_size >= need) {
        unsigned* hist = (unsigned*)(ws + o_hist);
        unsigned* starts = (unsigned*)(ws + o_starts);
        unsigned* cellid = (unsigned*)(ws + o_cellid);
        unsigned* rank = (unsigned*)(ws + o_rank);
        unsigned* sidx = (unsigned*)(ws + o_sidx);
        float* mk = (float*)(ws + o_mk);
        float4* sorted = (float4*)(ws + o_sorted);

        hipMemsetAsync(hist, 0, (size_t)4 * NC * 4, stream);

        dim3 gb((Pmax + 255) / 256, 4);
        grid_build<<<gb, 256, 0, stream>>>(c1, c2, P1, P2, hist, cellid, rank);
        grid_scan<<<4, 1024, 0, stream>>>(hist, starts);
        grid_scatter<<<gb, 256, 0, stream>>>(c1, c2, P1, P2, starts, cellid, rank,
                                             sorted, sidx);
        dim3 gq((Pmax + QBLK - 1) / QBLK, 4);
        grid_query<<<gq, QBLK, 0, stream>>>(P1, P2, starts, sorted, sidx, mk);

        reduce_all<<<1, 1024, 0, stream>>>(mk, P1, P2, (float*)d_out);
    } else {
        // fallback: brute force (r2 config)
        unsigned* mk = (unsigned*)(ws + o_mk);
        hipMemsetAsync(mk, 0xFF, (size_t)TP * 4, stream);
        dim3 g1((Pmax + BLOCK * QPT - 1) / (BLOCK * QPT),
                (Pmax + SEG - 1) / SEG, 2 * N);
        chamfer_pass1<<<g1, BLOCK, 0, stream>>>(c1, c2, P1, P2, mk);
        dim3 g2(P2A_BLOCKS, 4);
        pass2a_key<<<g2, 256, 0, stream>>>(mk, P1, P2, partial);
        pass2b<<<1, 64, 0, stream>>>(partial, P1, P2, (float*)d_out);
    }
}

// Round 8
// 142.790 us; speedup vs baseline: 7.5432x; 7.5432x over previous
//
#include <hip/hip_runtime.h>
#include <math.h>

// Chamfer distance, N=2, D=3 fp32 — grid-pruned exact NN, brick-parallel v4.
// r5-r7 post-mortem: every design with <=750 waves (one wave per 64 queries)
// was latency-bound (VALUBusy 1-3%, occupancy <3%). Fix: decompose by BRICK
// (2^3 cells), one 256-thread block per (brick, n, dir) -> 16384 blocks,
// 64/CU: latency structurally hidden. Per block: stage dilated 4^3-cell
// target region into LDS (<=16 contiguous rows, coalesced, ~380 pts avg,
// center max ~1100 < 2048 cap), each thread scans its own query against all
// staged candidates (broadcast ds_read_b128 + 4 VALU/pair). ~18M pairs total.
// Queries failing the margin-to-dilated-brick bound (~3%, sparse outskirts)
// are flagged; tail_brute (grid-stride, 1 block/flagged query, full exact
// scan, tree-reduce) finishes them. Exactness: margin bound (clamp is
// non-expansive; domain-edge faces exhaustive); tail exhaustive.
// Determinism: candidate SETs deterministic (counting sort; atomic ranks
// only permute within-cell order), fp min is order-independent, every mk
// entry has exactly one writer, fixed-order final reduction.

#define G 32
#define NC (G * G * G)
#define HLO -4.5f
#define HCELL 0.28125f
#define LDS_CAP 2048
#define TAILG 512
#define P2A_BLOCKS 6
#define P2A_PAD 8

__device__ __forceinline__ int cell_coord(float x) {
    int i = (int)floorf((x - HLO) * (32.0f / 9.0f));
    return min(max(i, 0), G - 1);
}

// ---------------- grid build / scan / scatter ----------------

__global__ __launch_bounds__(256) void grid_build(
    const float* __restrict__ c1, const float* __restrict__ c2,
    int P1, int P2, unsigned* __restrict__ hist,
    unsigned* __restrict__ cellid, unsigned* __restrict__ rank) {
    const int set = blockIdx.y;           // n*2 + cloud
    const int n = set >> 1, cl = set & 1;
    const int P = cl ? P2 : P1;
    const int i = blockIdx.x * 256 + threadIdx.x;
    if (i >= P) return;
    const float* p = (cl ? c2 + (size_t)n * P2 * 3 : c1 + (size_t)n * P1 * 3) + (size_t)i * 3;
    const int ix = cell_coord(p[0]), iy = cell_coord(p[1]), iz = cell_coord(p[2]);
    const unsigned c = ((unsigned)iz * G + iy) * G + ix;
    const unsigned r = atomicAdd(&hist[(size_t)set * NC + c], 1u);
    const int poff = n * (P1 + P2) + (cl ? P1 : 0);
    cellid[poff + i] = c;
    rank[poff + i] = r;
}

__global__ __launch_bounds__(1024) void grid_scan(
    const unsigned* __restrict__ hist, unsigned* __restrict__ starts) {
    const int set = blockIdx.x;
    const unsigned* h = hist + (size_t)set * NC;
    unsigned* st = starts + (size_t)set * (NC + 1);
    const int t = threadIdx.x;
    const int CH = NC / 1024;             // 32
    unsigned s = 0;
    for (int k = 0; k < CH; ++k) s += h[t * CH + k];
    __shared__ unsigned sd[1024];
    sd[t] = s;
    __syncthreads();
    for (int off = 1; off < 1024; off <<= 1) {
        unsigned v = (t >= off) ? sd[t - off] : 0u;
        __syncthreads();
        sd[t] += v;
        __syncthreads();
    }
    unsigned run = (t == 0) ? 0u : sd[t - 1];
    for (int k = 0; k < CH; ++k) {
        st[t * CH + k] = run;
        run += h[t * CH + k];
    }
    if (t == 1023) st[NC] = run;          // sentinel = total
}

__global__ __launch_bounds__(256) void grid_scatter(
    const float* __restrict__ c1, const float* __restrict__ c2,
    int P1, int P2, const unsigned* __restrict__ starts,
    const unsigned* __restrict__ cellid, const unsigned* __restrict__ rank,
    float4* __restrict__ sorted, unsigned* __restrict__ sidx) {
    const int set = blockIdx.y;
    const int n = set >> 1, cl = set & 1;
    const int P = cl ? P2 : P1;
    const int i = blockIdx.x * 256 + threadIdx.x;
    if (i >= P) return;
    const float* p = (cl ? c2 + (size_t)n * P2 * 3 : c1 + (size_t)n * P1 * 3) + (size_t)i * 3;
    const float x = p[0], y = p[1], z = p[2];
    const int poff = n * (P1 + P2) + (cl ? P1 : 0);
    const unsigned c = cellid[poff + i];
    const unsigned pos = starts[(size_t)set * (NC + 1) + c] + rank[poff + i];
    sorted[poff + pos] = make_float4(-2.f * x, -2.f * y, -2.f * z,
                                     fmaf(x, x, fmaf(y, y, z * z)));
    sidx[poff + pos] = i;
}

// ---------------- brick-parallel query ----------------

__global__ __launch_bounds__(256) void brick_query(
    int P1, int P2, const unsigned* __restrict__ starts,
    const float4* __restrict__ sorted, const unsigned* __restrict__ sidx,
    float* __restrict__ mk, unsigned* __restrict__ flag) {
    __shared__ float4 cand[LDS_CAP];      // 32 KB
    __shared__ unsigned rlo[16], rcnt[16], roff[17];
    __shared__ unsigned qlo_s[4], qoff_s[5];
    const int zz = blockIdx.y;            // n*2 + dir
    const int n = zz >> 1, dir = zz & 1;
    const int qs = n * 2 + dir, ts = n * 2 + (1 - dir);
    const int qoff = n * (P1 + P2) + (dir ? P1 : 0);
    const int toff = n * (P1 + P2) + (dir ? 0 : P1);
    const unsigned* qst = starts + (size_t)qs * (NC + 1);
    const unsigned* tst = starts + (size_t)ts * (NC + 1);
    const float4* T = sorted + toff;
    const float4* Qs = sorted + qoff;
    const int t = threadIdx.x;
    const int bx = blockIdx.x & 15, by = (blockIdx.x >> 4) & 15, bz = blockIdx.x >> 8;

    // query rows: 4 rows of 2 contiguous cells
    if (t < 4) {
        const int zc = 2 * bz + (t >> 1), yc = 2 * by + (t & 1);
        const int base = (zc * G + yc) * G + 2 * bx;
        const unsigned lo = qst[base];
        qlo_s[t] = lo;
        qoff_s[t] = qst[base + 2] - lo;   // temp: count
    }
    // target rows: dilated brick, <=16 rows of <=4 contiguous cells
    const int x0 = max(2 * bx - 1, 0), x1 = min(2 * bx + 2, G - 1);
    const int y0 = max(2 * by - 1, 0), y1 = min(2 * by + 2, G - 1);
    const int z0 = max(2 * bz - 1, 0), z1 = min(2 * bz + 2, G - 1);
    const int ny = y1 - y0 + 1;
    const int nrows = ny * (z1 - z0 + 1);
    if (t < nrows) {
        const int zc = z0 + t / ny, yc = y0 + t % ny;
        const int base = (zc * G + yc) * G;
        const unsigned lo = tst[base + x0];
        rlo[t] = lo;
        rcnt[t] = tst[base + x1 + 1] - lo;
    }
    __syncthreads();
    if (t == 0) {
        unsigned run = 0;
        for (int r = 0; r < nrows; ++r) { roff[r] = run; run += rcnt[r]; }
        roff[nrows] = run;
        unsigned qr = 0;
        for (int r = 0; r < 4; ++r) { unsigned c = qoff_s[r]; qoff_s[r] = qr; qr += c; }
        qoff_s[4] = qr;
    }
    __syncthreads();
    const unsigned nt = roff[nrows];
    const unsigned nq = qoff_s[4];
    if (nq == 0) return;
    const bool ovf = nt > LDS_CAP;
    if (!ovf) {
        const int g = t >> 4, l16 = t & 15;
        if (g < nrows) {
            const unsigned cnt = rcnt[g], lo = rlo[g], off = roff[g];
            for (unsigned k = l16; k < cnt; k += 16)
                cand[off + k] = T[lo + k];   // 16 consecutive lanes: coalesced
        }
    }
    __syncthreads();

    for (unsigned tq = t; tq < nq; tq += 256) {
        int r = 0;
        while (r < 3 && tq >= qoff_s[r + 1]) ++r;
        const unsigned qslot = qlo_s[r] + (tq - qoff_s[r]);
        const float4 q = Qs[qslot];
        const unsigned orig = sidx[qoff + qslot];
        if (ovf) { flag[qoff + orig] = 1u; continue; }
        const float ax = -0.5f * q.x, ay = -0.5f * q.y, az = -0.5f * q.z, qw = q.w;
        float best = INFINITY;
        unsigned k = 0;
        for (; k + 2 <= nt; k += 2) {       // uniform k: broadcast ds_read_b128
            float4 b0 = cand[k], b1 = cand[k + 1];
            float d0 = fmaf(ax, b0.x, fmaf(ay, b0.y, fmaf(az, b0.z, b0.w)));
            float d1 = fmaf(ax, b1.x, fmaf(ay, b1.y, fmaf(az, b1.z, b1.w)));
            best = fminf(fminf(best, d0), d1);
        }
        if (k < nt) {
            float4 b = cand[k];
            best = fminf(best, fmaf(ax, b.x, fmaf(ay, b.y, fmaf(az, b.z, b.w))));
        }
        // margin to scanned (dilated-brick) box; domain-edge faces exhaustive
        float mg = 1e30f;
        if (x0 > 0)     mg = fminf(mg, ax - (HLO + (float)x0 * HCELL));
        if (x1 < G - 1) mg = fminf(mg, (HLO + (float)(x1 + 1) * HCELL) - ax);
        if (y0 > 0)     mg = fminf(mg, ay - (HLO + (float)y0 * HCELL));
        if (y1 < G - 1) mg = fminf(mg, (HLO + (float)(y1 + 1) * HCELL) - ay);
        if (z0 > 0)     mg = fminf(mg, az - (HLO + (float)z0 * HCELL));
        if (z1 < G - 1) mg = fminf(mg, (HLO + (float)(z1 + 1) * HCELL) - az);
        const float d2 = qw + best;
        if (d2 <= mg * mg) mk[qoff + orig] = d2;
        else flag[qoff + orig] = 1u;
    }
}

// ---------------- exact tail: full scan for flagged queries ----------------

__global__ __launch_bounds__(256) void tail_brute(
    const float* __restrict__ c1, const float* __restrict__ c2,
    int P1, int P2, const float4* __restrict__ sorted,
    const unsigned* __restrict__ flag, float* __restrict__ mk) {
    const int zz = blockIdx.y;
    const int n = zz >> 1, dir = zz & 1;
    const int Pq = dir ? P2 : P1, Pt = dir ? P1 : P2;
    const int qoff = n * (P1 + P2) + (dir ? P1 : 0);
    const int toff = n * (P1 + P2) + (dir ? 0 : P1);
    const float* Q = dir ? c2 + (size_t)n * P2 * 3 : c1 + (size_t)n * P1 * 3;
    const float4* T = sorted + toff;
    const int t = threadIdx.x;
    __shared__ float red[256];
    for (int q = blockIdx.x; q < Pq; q += TAILG) {
        if (!flag[qoff + q]) continue;    // block-uniform
        const float ax = Q[(size_t)q * 3], ay = Q[(size_t)q * 3 + 1], az = Q[(size_t)q * 3 + 2];
        const float qw = fmaf(ax, ax, fmaf(ay, ay, az * az));
        float best = INFINITY;
        for (int k = t; k + 256 < Pt + 256; k += 512) {
            if (k < Pt) {
                float4 b = T[k];
                best = fminf(best, fmaf(ax, b.x, fmaf(ay, b.y, fmaf(az, b.z, b.w))));
            }
            int k2 = k + 256;
            if (k2 < Pt) {
                float4 b = T[k2];
                best = fminf(best, fmaf(ax, b.x, fmaf(ay, b.y, fmaf(az, b.z, b.w))));
            }
        }
        red[t] = best;
        __syncthreads();
        for (int o = 128; o > 0; o >>= 1) {
            if (t < o) red[t] = fminf(red[t], red[t + o]);
            __syncthreads();
        }
        if (t == 0) mk[qoff + q] = qw + red[0];
        __syncthreads();
    }
}

// ---------------- fused final reduction (deterministic fixed order) ----------

__global__ __launch_bounds__(1024) void reduce_all(
    const float* __restrict__ mk, int P1, int P2, float* __restrict__ out) {
    const int t = threadIdx.x;
    const int off[4] = {0, P1, P1 + P2, P1 + P2 + P1};
    const int len[4] = {P1, P2, P1, P2};
    float acc[4];
    #pragma unroll
    for (int z = 0; z < 4; ++z) {
        float s = 0.f;
        const float* p = mk + off[z];
        for (int i = t; i < len[z]; i += 1024) s += p[i];
        acc[z] = s;
    }
    __shared__ float red[1024];
    float res[4];
    for (int z = 0; z < 4; ++z) {
        red[t] = acc[z];
        __syncthreads();
        for (int o = 512; o > 0; o >>= 1) {
            if (t < o) red[t] += red[t + o];
            __syncthreads();
        }
        res[z] = red[0];
        __syncthreads();
    }
    if (t == 0) {
        out[0] = res[0] / (float)P1 + res[1] / (float)P2;
        out[1] = res[2] / (float)P1 + res[3] / (float)P2;
    }
}

// ---------------- fallback brute-force path (r2 config) ----------------

#define BLOCK 256
#define QPT 4
#define SEG 384

__device__ __forceinline__ unsigned fkey(float f) {
    unsigned u = __float_as_uint(f);
    unsigned mask = (unsigned)((int)u >> 31) | 0x80000000u;
    return u ^ mask;
}
__device__ __forceinline__ float fdec(unsigned k) {
    unsigned mask = (k & 0x80000000u) ? 0x80000000u : 0xFFFFFFFFu;
    return __uint_as_float(k ^ mask);
}

__global__ __launch_bounds__(BLOCK) void chamfer_pass1(
    const float* __restrict__ c1, const float* __restrict__ c2,
    int P1, int P2, unsigned* __restrict__ mk_all) {
    const int z = blockIdx.z;
    const int n = z >> 1, dir = z & 1;
    const int Pq = dir ? P2 : P1;
    const int Pt = dir ? P1 : P2;
    const float* Q = (dir ? c2 : c1) + (size_t)n * Pq * 3;
    const float* T = (dir ? c1 : c2) + (size_t)n * Pt * 3;
    unsigned* mk = mk_all + (size_t)n * (P1 + P2) + (dir ? P1 : 0);

    __shared__ float4 tile[SEG];
    const int t0 = blockIdx.y * SEG;
    const int nt = Pt - t0;
    for (int j = threadIdx.x; j < SEG; j += BLOCK) {
        float4 v;
        if (j < nt) {
            const float* p = T + (size_t)(t0 + j) * 3;
            float x = p[0], y = p[1], w = p[2];
            v = make_float4(-2.f * x, -2.f * y, -2.f * w,
                            fmaf(x, x, fmaf(y, y, w * w)));
        } else {
            v = make_float4(0.f, 0.f, 0.f, INFINITY);
        }
        tile[j] = v;
    }
    __syncthreads();

    const int qbase = blockIdx.x * (BLOCK * QPT) + threadIdx.x;
    float ax[QPT], ay[QPT], az[QPT], sq[QPT], m[QPT];
    #pragma unroll
    for (int k = 0; k < QPT; ++k) {
        const int qi = qbase + k * BLOCK;
        ax[k] = 0.f; ay[k] = 0.f; az[k] = 0.f;
        if (qi < Pq) {
            const float* p = Q + (size_t)qi * 3;
            ax[k] = p[0]; ay[k] = p[1]; az[k] = p[2];
        }
        sq[k] = fmaf(ax[k], ax[k], fmaf(ay[k], ay[k], az[k] * az[k]));
        m[k] = INFINITY;
    }
    #pragma unroll 4
    for (int j = 0; j < SEG; j += 2) {
        float4 b0 = tile[j];
        float4 b1 = tile[j + 1];
        #pragma unroll
        for (int k = 0; k < QPT; ++k) {
            float d0 = fmaf(ax[k], b0.x, fmaf(ay[k], b0.y, fmaf(az[k], b0.z, b0.w)));
            float d1 = fmaf(ax[k], b1.x, fmaf(ay[k], b1.y, fmaf(az[k], b1.z, b1.w)));
            m[k] = fminf(fminf(m[k], d0), d1);
        }
    }
    #pragma unroll
    for (int k = 0; k < QPT; ++k) {
        const int qi = qbase + k * BLOCK;
        if (qi < Pq) atomicMin(&mk[qi], fkey(sq[k] + m[k]));
    }
}

__global__ __launch_bounds__(256) void pass2a_key(
    const unsigned* __restrict__ mk_all, int P1, int P2,
    float* __restrict__ partial) {
    const int z = blockIdx.y;
    const int b = blockIdx.x;
    const int n = z >> 1, dir = z & 1;
    const int Pq = dir ? P2 : P1;
    const unsigned* mk = mk_all + (size_t)n * (P1 + P2) + (dir ? P1 : 0);
    const int span = (Pq + P2A_BLOCKS - 1) / P2A_BLOCKS;
    const int lo = b * span;
    const int hi = min(lo + span, Pq);
    float s = 0.f;
    for (int q = lo + threadIdx.x; q < hi; q += 256) s += fdec(mk[q]);
    __shared__ float red[256];
    red[threadIdx.x] = s;
    __syncthreads();
    for (int off = 128; off > 0; off >>= 1) {
        if (threadIdx.x < off) red[threadIdx.x] += red[threadIdx.x + off];
        __syncthreads();
    }
    if (threadIdx.x == 0) partial[z * P2A_PAD + b] = red[0];
}

__global__ void pass2b(const float* __restrict__ partial,
                       int P1, int P2, float* __restrict__ out) {
    int n = threadIdx.x;
    if (n < 2) {
        float sA = 0.f, sB = 0.f;
        for (int b = 0; b < P2A_BLOCKS; ++b) {
            sA += partial[(n * 2 + 0) * P2A_PAD + b];
            sB += partial[(n * 2 + 1) * P2A_PAD + b];
        }
        out[n] = sA / (float)P1 + sB / (float)P2;
    }
}

// ---------------- launch ----------------

static inline size_t al256(size_t x) { return (x + 255) & ~(size_t)255; }

extern "C" void kernel_launch(void* const* d_in, const int* in_sizes, int n_in,
                              void* d_out, int out_size, void* d_ws, size_t ws_size,
                              hipStream_t stream) {
    const float* c1 = (const float*)d_in[0];
    const float* c2 = (const float*)d_in[1];
    const int N = 2;
    const int P1 = in_sizes[0] / (N * 3);
    const int P2 = in_sizes[1] / (N * 3);
    const int TP = N * (P1 + P2);
    const int Pmax = P1 > P2 ? P1 : P2;

    // ws layout (256-aligned); hist+flag contiguous for a single memset
    size_t o_hist = 0;
    size_t o_flag = al256(o_hist + (size_t)4 * NC * 4);
    size_t o_starts = al256(o_flag + (size_t)TP * 4);
    size_t o_cellid = al256(o_starts + (size_t)4 * (NC + 1) * 4);
    size_t o_rank = al256(o_cellid + (size_t)TP * 4);
    size_t o_sidx = al256(o_rank + (size_t)TP * 4);
    size_t o_mk = al256(o_sidx + (size_t)TP * 4);
    size_t o_part = al256(o_mk + (size_t)TP * 4);
    size_t o_sorted = al256(o_part + (size_t)4 * P2A_PAD * 4);
    size_t need = o_sorted + (size_t)TP * 16;

    char* ws = (char*)d_ws;
    float* partial = (float*)(ws + o_part);

    if (ws_size >= need) {
        unsigned* hist = (unsigned*)(ws + o_hist);
        unsigned* flag = (unsigned*)(ws + o_flag);
        unsigned* starts = (unsigned*)(ws + o_starts);
        unsigned* cellid = (unsigned*)(ws + o_cellid);
        unsigned* rank = (unsigned*)(ws + o_rank);
        unsigned* sidx = (unsigned*)(ws + o_sidx);
        float* mk = (float*)(ws + o_mk);
        float4* sorted = (float4*)(ws + o_sorted);

        hipMemsetAsync(ws, 0, o_flag + (size_t)TP * 4, stream);  // hist + flag

        dim3 gb((Pmax + 255) / 256, 4);
        grid_build<<<gb, 256, 0, stream>>>(c1, c2, P1, P2, hist, cellid, rank);
        grid_scan<<<4, 1024, 0, stream>>>(hist, starts);
        grid_scatter<<<gb, 256, 0, stream>>>(c1, c2, P1, P2, starts, cellid, rank,
                                             sorted, sidx);
        brick_query<<<dim3(4096, 4), 256, 0, stream>>>(P1, P2, starts, sorted,
                                                       sidx, mk, flag);
        tail_brute<<<dim3(TAILG, 4), 256, 0, stream>>>(c1, c2, P1, P2, sorted,
                                                       flag, mk);
        reduce_all<<<1, 1024, 0, stream>>>(mk, P1, P2, (float*)d_out);
    } else {
        // fallback: brute force (r2 config)
        unsigned* mk = (unsigned*)(ws + o_mk);
        hipMemsetAsync(mk, 0xFF, (size_t)TP * 4, stream);
        dim3 g1((Pmax + BLOCK * QPT - 1) / (BLOCK * QPT),
                (Pmax + SEG - 1) / SEG, 2 * N);
        chamfer_pass1<<<g1, BLOCK, 0, stream>>>(c1, c2, P1, P2, mk);
        dim3 g2(P2A_BLOCKS, 4);
        pass2a_key<<<g2, 256, 0, stream>>>(mk, P1, P2, partial);
        pass2b<<<1, 64, 0, stream>>>(partial, P1, P2, (float*)d_out);
    }
}